// Round 2
// baseline (805.467 us; speedup 1.0000x reference)
//
#include <hip/hip_runtime.h>
#include <cmath>

#define H_ 128
#define W_ 128
#define HW_ 16384
#define C_ 64
#define N_ 8
#define BN_EPS 1e-5f

typedef __attribute__((ext_vector_type(8))) short short8;
typedef __attribute__((ext_vector_type(4))) float float4_;

__device__ inline short f2bf(float f) {
    unsigned u = __builtin_bit_cast(unsigned, f);
    u += 0x7fffu + ((u >> 16) & 1u);     // RNE
    return (short)(u >> 16);
}
__device__ inline float bf2f(short s) {
    unsigned u = ((unsigned)(unsigned short)s) << 16;
    return __builtin_bit_cast(float, u);
}

// ---- workspace layout (bytes) ----
// off_buf fp32 [8][18][16384]          @ 0          size 9,437,184
// wdefT  fp32 [(k*64+c)*64+o]          @ 9,437,184  size 147,456
// xb8    bf16 [8][8][16384][8]         @ 9,584,640  size 16,777,216
// xr8    bf16 [8][8][16384][8]         @ 26,361,856 size 16,777,216
// BT27   bf16 [32][584]                @ 43,139,072 size 37,376
// BT9    bf16 [16][584]                @ 43,176,448 size 18,688
#define OFFB_OFS   0
#define WDEFT_OFS  9437184
#define XB8_OFS    9584640
#define XR8_OFS    26361856
#define BT27_OFS   43139072
#define BT9_OFS    43176448

// ---------------- weight prep ----------------
// wdefT[(k*64+c)*64+o] = w_def[o][c][k]
// BT27[oc][K=t*64+c] = w_off[oc][c][t]  (oc padded to 32, K padded to 584, zero-fill)
// BT9 [oc][K=t*64+c] = w1[oc][c][t]     (oc padded to 16)
__global__ __launch_bounds__(256) void prep_w(
    const float* __restrict__ w_off, const float* __restrict__ w_def,
    const float* __restrict__ w1, float* __restrict__ wdefT,
    short* __restrict__ bt27, short* __restrict__ bt9)
{
    int i = blockIdx.x * 256 + threadIdx.x;
    if (i < 36864) {
        int k = i >> 12, r = i & 4095, c = r >> 6, o = r & 63;
        wdefT[i] = w_def[o*576 + c*9 + k];
    } else if (i < 36864 + 18688) {
        int j = i - 36864;
        int oc = j / 584, K = j - oc*584;
        float v = 0.f;
        if (oc < 27 && K < 576) { int t = K >> 6, c = K & 63; v = w_off[oc*576 + c*9 + t]; }
        bt27[j] = f2bf(v);
    } else if (i < 36864 + 18688 + 9344) {
        int j = i - 36864 - 18688;
        int oc = j / 584, K = j - oc*584;
        float v = 0.f;
        if (oc < 9 && K < 576) { int t = K >> 6, c = K & 63; v = w1[oc*576 + c*9 + t]; }
        bt9[j] = f2bf(v);
    }
}

// ---------------- x -> NC8HW8 bf16 ----------------
__global__ __launch_bounds__(256) void convert_x(
    const float* __restrict__ x, short8* __restrict__ xb8)
{
    int idx = blockIdx.x * 256 + threadIdx.x;     // [n][c8][pix]
    int pix = idx & (HW_-1);
    int c8  = (idx >> 14) & 7;
    int n   = idx >> 17;
    const float* xp = x + ((size_t)(n*64 + c8*8))*HW_ + pix;
    short8 v;
    #pragma unroll
    for (int j = 0; j < 8; j++) v[j] = f2bf(xp[j*HW_]);
    xb8[idx] = v;
}

// ---------------- conv27 as implicit-GEMM bf16 MFMA ----------------
// block: 16x16 px tile, 256 threads = 4 waves. M=256 px, N=32 (27 used), K=576.
__global__ __launch_bounds__(256) void conv27_mfma(
    const short8* __restrict__ xb8, const short* __restrict__ bt_g,
    float* __restrict__ off_buf, float* __restrict__ filt_out)
{
    __shared__ short8 patch[8*325];   // [c8][py*18+px], plane stride 325 (pad)
    __shared__ short8 btl[32*73];     // [oc][K/8]
    const int tid = threadIdx.x;
    const int bx = blockIdx.x, by = blockIdx.y, n = blockIdx.z;

    for (int i = tid; i < 2336; i += 256) btl[i] = ((const short8*)bt_g)[i];
    for (int i = tid; i < 2592; i += 256) {
        int c8 = i / 324, r = i - c8*324;
        int py = r / 18, px = r - py*18;
        int gy = by*16 - 1 + py, gx = bx*16 - 1 + px;
        short8 v = {0,0,0,0,0,0,0,0};
        if ((unsigned)gy < 128u && (unsigned)gx < 128u)
            v = xb8[(size_t)(n*8 + c8)*HW_ + gy*W_ + gx];
        patch[c8*325 + py*18 + px] = v;
    }
    __syncthreads();

    const int lane = tid & 63, wid = tid >> 6;
    const int q = lane >> 4, col = lane & 15;
    float4_ acc[4][2];
    #pragma unroll
    for (int i = 0; i < 4; i++) {
        acc[i][0] = (float4_){0.f,0.f,0.f,0.f};
        acc[i][1] = (float4_){0.f,0.f,0.f,0.f};
    }

    #pragma unroll 2
    for (int k0 = 0; k0 < 18; k0++) {
        int t = k0 >> 1;
        int dy = t/3, dx = t - dy*3;
        int c8 = (k0 & 1)*4 + q;
        short8 b0 = btl[col*73 + k0*4 + q];
        short8 b1 = btl[(16 + col)*73 + k0*4 + q];
        #pragma unroll
        for (int i = 0; i < 4; i++) {
            int mt = wid*4 + i;
            short8 a = patch[c8*325 + (mt + dy)*18 + (col + dx)];
            acc[i][0] = __builtin_amdgcn_mfma_f32_16x16x32_bf16(a, b0, acc[i][0], 0,0,0);
            acc[i][1] = __builtin_amdgcn_mfma_f32_16x16x32_bf16(a, b1, acc[i][1], 0,0,0);
        }
    }

    // C/D: col = lane&15 (=oc-offset), row = q*4+reg (=tx), M-tile = ty
    #pragma unroll
    for (int i = 0; i < 4; i++) {
        int ty = wid*4 + i;
        #pragma unroll
        for (int nt = 0; nt < 2; nt++) {
            int oc = nt*16 + col;
            if (oc >= 27) continue;
            #pragma unroll
            for (int reg = 0; reg < 4; reg++) {
                int tx = q*4 + reg;
                int pix = (by*16 + ty)*W_ + bx*16 + tx;
                float v = acc[i][nt][reg];
                if (oc < 18) off_buf[((size_t)n*18 + oc)*HW_ + pix] = v;
                else         filt_out[((size_t)n*9 + (oc-18))*HW_ + pix] = v;
            }
        }
    }
}

// ---------------- deformable conv, channel-split x4 ----------------
__global__ __launch_bounds__(256) void deform_split(
    const float* __restrict__ x, const float* __restrict__ off_buf,
    const float* __restrict__ wT, const short8* __restrict__ xb8,
    short8* __restrict__ xr8)
{
    const int tid = threadIdx.x;
    const int og  = __builtin_amdgcn_readfirstlane(tid >> 6);  // wave-uniform oc group
    const int pl  = blockIdx.x*64 + (tid & 63);
    const int n   = blockIdx.y;
    const int hh  = pl >> 7, ww = pl & 127;
    const float* xb = x + (size_t)n * C_ * HW_;
    const float* ob = off_buf + (size_t)n * 18 * HW_ + pl;

    float acc[16];
    #pragma unroll
    for (int i = 0; i < 16; i++) acc[i] = 0.f;

    #pragma unroll 1
    for (int k = 0; k < 9; k++) {
        float offy = ob[(2*k) * HW_];
        float offx = ob[(2*k+1) * HW_];
        float py = (float)(hh + k/3 - 1) + offy;
        float px = (float)(ww + k%3 - 1) + offx;
        float y0f = floorf(py), x0f = floorf(px);
        float wy1 = py - y0f, wx1 = px - x0f;
        float wy0 = 1.f - wy1, wx0 = 1.f - wx1;
        int y0 = (int)y0f, x0 = (int)x0f;
        int y1 = y0 + 1,   x1 = x0 + 1;
        float vy0 = ((unsigned)y0 < (unsigned)H_) ? 1.f : 0.f;
        float vy1 = ((unsigned)y1 < (unsigned)H_) ? 1.f : 0.f;
        float vx0 = ((unsigned)x0 < (unsigned)W_) ? 1.f : 0.f;
        float vx1 = ((unsigned)x1 < (unsigned)W_) ? 1.f : 0.f;
        float w00 = wy0*wx0*vy0*vx0, w01 = wy0*wx1*vy0*vx1;
        float w10 = wy1*wx0*vy1*vx0, w11 = wy1*wx1*vy1*vx1;
        int cy0 = min(max(y0, 0), H_-1), cy1 = min(max(y1, 0), H_-1);
        int cx0 = min(max(x0, 0), W_-1), cx1 = min(max(x1, 0), W_-1);
        int i00 = cy0*W_ + cx0, i01 = cy0*W_ + cx1;
        int i10 = cy1*W_ + cx0, i11 = cy1*W_ + cx1;

        float p00 = xb[i00], p01 = xb[i01], p10 = xb[i10], p11 = xb[i11];
        const float* wpk = wT + (k*64)*64 + og*16;
        #pragma unroll 2
        for (int c = 0; c < C_; c++) {
            float s = p00*w00 + p01*w01 + p10*w10 + p11*w11;
            if (c + 1 < C_) {
                const float* xq = xb + (c+1) * HW_;
                p00 = xq[i00]; p01 = xq[i01]; p10 = xq[i10]; p11 = xq[i11];
            }
            const float* wp = wpk + c*64;        // uniform -> scalar loads
            #pragma unroll
            for (int o = 0; o < 16; o++)
                acc[o] = fmaf(s, wp[o], acc[o]);
        }
    }

    // residual add (bf16 x) + store NC8HW8 bf16
    #pragma unroll
    for (int half = 0; half < 2; half++) {
        int c8 = og*2 + half;
        size_t idx = (size_t)(n*8 + c8)*HW_ + pl;
        short8 r = xb8[idx];
        short8 o8;
        #pragma unroll
        for (int j = 0; j < 8; j++) o8[j] = f2bf(acc[half*8 + j] + bf2f(r[j]));
        xr8[idx] = o8;
    }
}

// ---------------- conv9 + BN + ReLU as implicit-GEMM bf16 MFMA ----------------
__global__ __launch_bounds__(256) void conv9_mfma(
    const short8* __restrict__ xr8, const short* __restrict__ bt_g,
    const float* __restrict__ gamma, const float* __restrict__ beta,
    const float* __restrict__ mean, const float* __restrict__ var,
    float* __restrict__ out)
{
    __shared__ short8 patch[8*325];
    __shared__ short8 btl[16*73];
    const int tid = threadIdx.x;
    const int bx = blockIdx.x, by = blockIdx.y, n = blockIdx.z;

    for (int i = tid; i < 1168; i += 256) btl[i] = ((const short8*)bt_g)[i];
    for (int i = tid; i < 2592; i += 256) {
        int c8 = i / 324, r = i - c8*324;
        int py = r / 18, px = r - py*18;
        int gy = by*16 - 1 + py, gx = bx*16 - 1 + px;
        short8 v = {0,0,0,0,0,0,0,0};
        if ((unsigned)gy < 128u && (unsigned)gx < 128u)
            v = xr8[(size_t)(n*8 + c8)*HW_ + gy*W_ + gx];
        patch[c8*325 + py*18 + px] = v;
    }
    __syncthreads();

    const int lane = tid & 63, wid = tid >> 6;
    const int q = lane >> 4, col = lane & 15;
    float4_ acc[4];
    #pragma unroll
    for (int i = 0; i < 4; i++) acc[i] = (float4_){0.f,0.f,0.f,0.f};

    #pragma unroll 2
    for (int k0 = 0; k0 < 18; k0++) {
        int t = k0 >> 1;
        int dy = t/3, dx = t - dy*3;
        int c8 = (k0 & 1)*4 + q;
        short8 b0 = btl[col*73 + k0*4 + q];
        #pragma unroll
        for (int i = 0; i < 4; i++) {
            int mt = wid*4 + i;
            short8 a = patch[c8*325 + (mt + dy)*18 + (col + dx)];
            acc[i] = __builtin_amdgcn_mfma_f32_16x16x32_bf16(a, b0, acc[i], 0,0,0);
        }
    }

    float sc = 0.f, sh = 0.f;
    if (col < 9) {
        sc = gamma[col] * rsqrtf(var[col] + BN_EPS);
        sh = beta[col] - mean[col] * sc;
    }
    #pragma unroll
    for (int i = 0; i < 4; i++) {
        int ty = wid*4 + i;
        if (col < 9) {
            #pragma unroll
            for (int reg = 0; reg < 4; reg++) {
                int tx = q*4 + reg;
                int pix = (by*16 + ty)*W_ + bx*16 + tx;
                float h = fmaxf(fmaf(acc[i][reg], sc, sh), 0.f);
                out[((size_t)n*9 + col)*HW_ + pix] = h;
            }
        }
    }
}

extern "C" void kernel_launch(void* const* d_in, const int* in_sizes, int n_in,
                              void* d_out, int out_size, void* d_ws, size_t ws_size,
                              hipStream_t stream)
{
    const float* x     = (const float*)d_in[0];
    const float* w_off = (const float*)d_in[1];
    const float* w_def = (const float*)d_in[2];
    const float* w1    = (const float*)d_in[3];
    const float* gamma = (const float*)d_in[4];
    const float* beta  = (const float*)d_in[5];
    const float* mean  = (const float*)d_in[6];
    const float* var   = (const float*)d_in[7];
    float* out = (float*)d_out;

    char* ws = (char*)d_ws;
    float*  off_buf = (float*)(ws + OFFB_OFS);
    float*  wdefT   = (float*)(ws + WDEFT_OFS);
    short8* xb8     = (short8*)(ws + XB8_OFS);
    short8* xr8     = (short8*)(ws + XR8_OFS);
    short*  bt27    = (short*)(ws + BT27_OFS);
    short*  bt9     = (short*)(ws + BT9_OFS);

    float* h_out    = out;
    float* filt_out = out + (size_t)N_ * 9 * HW_;

    prep_w<<<dim3(254), dim3(256), 0, stream>>>(w_off, w_def, w1, wdefT, bt27, bt9);
    convert_x<<<dim3(4096), dim3(256), 0, stream>>>(x, xb8);

    dim3 cgrid(8, 8, 8);
    conv27_mfma<<<cgrid, dim3(256), 0, stream>>>(xb8, bt27, off_buf, filt_out);
    deform_split<<<dim3(256, 8), dim3(256), 0, stream>>>(x, off_buf, wdefT, xb8, xr8);
    conv9_mfma<<<cgrid, dim3(256), 0, stream>>>(xr8, bt9, gamma, beta, mean, var, h_out);
}

// Round 3
// 190.675 us; speedup vs baseline: 4.2243x; 4.2243x over previous
//
#include <hip/hip_runtime.h>
#include <cmath>

#define H_ 128
#define W_ 128
#define HW_ 16384
#define C_ 64
#define N_ 8
#define BN_EPS 1e-5f

typedef __attribute__((ext_vector_type(8))) short short8;
typedef __attribute__((ext_vector_type(4))) float float4_;

__device__ inline short f2bf(float f) {
    unsigned u = __builtin_bit_cast(unsigned, f);
    u += 0x7fffu + ((u >> 16) & 1u);     // RNE
    return (short)(u >> 16);
}
__device__ inline float bf2f(short s) {
    unsigned u = ((unsigned)(unsigned short)s) << 16;
    return __builtin_bit_cast(float, u);
}

// ---- workspace layout (bytes) ----
// off_buf fp32 [8][18][16384]   @ 0          size  9,437,184
// xb8    bf16 [8][8][16384][8]  @ 9,437,184  size 16,777,216
// xr8    bf16 [8][8][16384][8]  @ 26,214,400 size 16,777,216
// wdefB  bf16 [64][576]         @ 42,991,616 size     73,728
// BT27   bf16 [32][584]         @ 43,065,344 size     37,376
// BT9    bf16 [16][584]         @ 43,102,720 size     18,688
#define OFFB_OFS   0
#define XB8_OFS    9437184
#define XR8_OFS    26214400
#define WDEFB_OFS  42991616
#define BT27_OFS   43065344
#define BT9_OFS    43102720

// ---------------- weight prep ----------------
// wdefB[o][t*64+c] = w_def[o][c][t]   (bf16, row = 576 = 72 short8)
// BT27[oc][K=t*64+c] = w_off[oc][c][t]  (oc pad 32, K pad 584)
// BT9 [oc][K=t*64+c] = w1[oc][c][t]     (oc pad 16)
__global__ __launch_bounds__(256) void prep_w(
    const float* __restrict__ w_off, const float* __restrict__ w_def,
    const float* __restrict__ w1, short* __restrict__ wdefB,
    short* __restrict__ bt27, short* __restrict__ bt9)
{
    int i = blockIdx.x * 256 + threadIdx.x;
    if (i < 36864) {
        int o = i / 576, r = i - o*576, t = r >> 6, c = r & 63;
        wdefB[i] = f2bf(w_def[o*576 + c*9 + t]);
    } else if (i < 36864 + 18688) {
        int j = i - 36864;
        int oc = j / 584, K = j - oc*584;
        float v = 0.f;
        if (oc < 27 && K < 576) { int t = K >> 6, c = K & 63; v = w_off[oc*576 + c*9 + t]; }
        bt27[j] = f2bf(v);
    } else if (i < 36864 + 18688 + 9344) {
        int j = i - 36864 - 18688;
        int oc = j / 584, K = j - oc*584;
        float v = 0.f;
        if (oc < 9 && K < 576) { int t = K >> 6, c = K & 63; v = w1[oc*576 + c*9 + t]; }
        bt9[j] = f2bf(v);
    }
}

// ---------------- x -> NC8HW8 bf16 ----------------
__global__ __launch_bounds__(256) void convert_x(
    const float* __restrict__ x, short8* __restrict__ xb8)
{
    int idx = blockIdx.x * 256 + threadIdx.x;     // [n][c8][pix]
    int pix = idx & (HW_-1);
    int c8  = (idx >> 14) & 7;
    int n   = idx >> 17;
    const float* xp = x + ((size_t)(n*64 + c8*8))*HW_ + pix;
    short8 v;
    #pragma unroll
    for (int j = 0; j < 8; j++) v[j] = f2bf(xp[j*HW_]);
    xb8[idx] = v;
}

// ---------------- conv27 as implicit-GEMM bf16 MFMA ----------------
__global__ __launch_bounds__(256) void conv27_mfma(
    const short8* __restrict__ xb8, const short* __restrict__ bt_g,
    float* __restrict__ off_buf, float* __restrict__ filt_out)
{
    __shared__ short8 patch[8*325];   // [c8][py*18+px], plane stride 325
    __shared__ short8 btl[32*73];     // [oc][K/8]
    const int tid = threadIdx.x;
    const int bx = blockIdx.x, by = blockIdx.y, n = blockIdx.z;

    for (int i = tid; i < 2336; i += 256) btl[i] = ((const short8*)bt_g)[i];
    for (int i = tid; i < 2592; i += 256) {
        int c8 = i / 324, r = i - c8*324;
        int py = r / 18, px = r - py*18;
        int gy = by*16 - 1 + py, gx = bx*16 - 1 + px;
        short8 v = {0,0,0,0,0,0,0,0};
        if ((unsigned)gy < 128u && (unsigned)gx < 128u)
            v = xb8[(size_t)(n*8 + c8)*HW_ + gy*W_ + gx];
        patch[c8*325 + py*18 + px] = v;
    }
    __syncthreads();

    const int lane = tid & 63, wid = tid >> 6;
    const int q = lane >> 4, col = lane & 15;
    float4_ acc[4][2];
    #pragma unroll
    for (int i = 0; i < 4; i++) {
        acc[i][0] = (float4_){0.f,0.f,0.f,0.f};
        acc[i][1] = (float4_){0.f,0.f,0.f,0.f};
    }

    #pragma unroll 2
    for (int k0 = 0; k0 < 18; k0++) {
        int t = k0 >> 1;
        int dy = t/3, dx = t - dy*3;
        int c8 = (k0 & 1)*4 + q;
        short8 b0 = btl[col*73 + k0*4 + q];
        short8 b1 = btl[(16 + col)*73 + k0*4 + q];
        #pragma unroll
        for (int i = 0; i < 4; i++) {
            int mt = wid*4 + i;
            short8 a = patch[c8*325 + (mt + dy)*18 + (col + dx)];
            acc[i][0] = __builtin_amdgcn_mfma_f32_16x16x32_bf16(a, b0, acc[i][0], 0,0,0);
            acc[i][1] = __builtin_amdgcn_mfma_f32_16x16x32_bf16(a, b1, acc[i][1], 0,0,0);
        }
    }

    #pragma unroll
    for (int i = 0; i < 4; i++) {
        int ty = wid*4 + i;
        #pragma unroll
        for (int nt = 0; nt < 2; nt++) {
            int oc = nt*16 + col;
            if (oc >= 27) continue;
            #pragma unroll
            for (int reg = 0; reg < 4; reg++) {
                int tx = q*4 + reg;
                int pix = (by*16 + ty)*W_ + bx*16 + tx;
                float v = acc[i][nt][reg];
                if (oc < 18) off_buf[((size_t)n*18 + oc)*HW_ + pix] = v;
                else         filt_out[((size_t)n*9 + (oc-18))*HW_ + pix] = v;
            }
        }
    }
}

// ---------------- deformable conv as MFMA GEMM, register-direct A ----------------
// block = 16x16 px tile (4 waves), M=256 (64/wave), N=64, K=576 (t*64+c).
// Each lane gathers exactly its A-fragment: pixel = (wid*4+i, lane&15),
// channels c8 = ks*4+q, via one dwordx4 per bilinear corner from xb8.
__global__ __launch_bounds__(256, 2) void deform_mfma(
    const float* __restrict__ off_buf, const short8* __restrict__ xb8,
    const short8* __restrict__ wdefB, short* __restrict__ xr8s)
{
    const int tid = threadIdx.x;
    const int bx = blockIdx.x, by = blockIdx.y, n = blockIdx.z;
    const int lane = tid & 63, wid = tid >> 6;
    const int q = lane >> 4, col = lane & 15;
    const float*  ob    = off_buf + (size_t)n*18*HW_;
    const short8* xbase = xb8 + (size_t)n*8*HW_;
    const short*  xbs   = (const short*)xbase;

    float4_ acc[4][4];
    #pragma unroll
    for (int i = 0; i < 4; i++)
        #pragma unroll
        for (int nt = 0; nt < 4; nt++) acc[i][nt] = (float4_){0.f,0.f,0.f,0.f};

    #pragma unroll 1
    for (int t = 0; t < 9; t++) {
        const int dy = t/3 - 1, dx = t - (t/3)*3 - 1;
        short8 afrag[4][2];
        #pragma unroll
        for (int i = 0; i < 4; i++) {
            const int gy = by*16 + wid*4 + i;
            const int gx = bx*16 + col;
            const int pix = gy*W_ + gx;
            float offy = ob[(2*t)*HW_ + pix];
            float offx = ob[(2*t+1)*HW_ + pix];
            float py = (float)(gy + dy) + offy;
            float px = (float)(gx + dx) + offx;
            float y0f = floorf(py), x0f = floorf(px);
            float wy1 = py - y0f, wx1 = px - x0f;
            float wy0 = 1.f - wy1, wx0 = 1.f - wx1;
            int y0 = (int)y0f, x0 = (int)x0f;
            int y1 = y0 + 1,   x1 = x0 + 1;
            float vy0 = ((unsigned)y0 < (unsigned)H_) ? 1.f : 0.f;
            float vy1 = ((unsigned)y1 < (unsigned)H_) ? 1.f : 0.f;
            float vx0 = ((unsigned)x0 < (unsigned)W_) ? 1.f : 0.f;
            float vx1 = ((unsigned)x1 < (unsigned)W_) ? 1.f : 0.f;
            float w00 = wy0*wx0*vy0*vx0, w01 = wy0*wx1*vy0*vx1;
            float w10 = wy1*wx0*vy1*vx0, w11 = wy1*wx1*vy1*vx1;
            int cy0 = min(max(y0, 0), H_-1), cy1 = min(max(y1, 0), H_-1);
            int cx0 = min(max(x0, 0), W_-1), cx1 = min(max(x1, 0), W_-1);
            int i00 = cy0*W_ + cx0, i01 = cy0*W_ + cx1;
            int i10 = cy1*W_ + cx0, i11 = cy1*W_ + cx1;
            #pragma unroll
            for (int ks = 0; ks < 2; ks++) {
                const short8* xg = xbase + (size_t)(ks*4 + q)*HW_;
                short8 p00 = xg[i00], p01 = xg[i01];
                short8 p10 = xg[i10], p11 = xg[i11];
                short8 a;
                #pragma unroll
                for (int j = 0; j < 8; j++) {
                    float s = bf2f(p00[j])*w00 + bf2f(p01[j])*w01
                            + bf2f(p10[j])*w10 + bf2f(p11[j])*w11;
                    a[j] = f2bf(s);
                }
                afrag[i][ks] = a;
            }
        }
        #pragma unroll
        for (int ks = 0; ks < 2; ks++) {
            #pragma unroll
            for (int nt = 0; nt < 4; nt++) {
                short8 b = wdefB[(size_t)(nt*16 + col)*72 + t*8 + ks*4 + q];
                #pragma unroll
                for (int i = 0; i < 4; i++)
                    acc[i][nt] = __builtin_amdgcn_mfma_f32_16x16x32_bf16(
                        afrag[i][ks], b, acc[i][nt], 0,0,0);
            }
        }
    }

    // epilogue: D col = lane&15 -> oc offset, row = q*4+reg -> tx; +bf16 residual
    short* xout = xr8s + (size_t)n*8*HW_*8;
    #pragma unroll
    for (int i = 0; i < 4; i++) {
        const int gy = by*16 + wid*4 + i;
        #pragma unroll
        for (int nt = 0; nt < 4; nt++) {
            const int o = nt*16 + col;
            #pragma unroll
            for (int reg = 0; reg < 4; reg++) {
                const int gx = bx*16 + q*4 + reg;
                const int pix = gy*W_ + gx;
                size_t si = ((size_t)(o >> 3)*HW_ + pix)*8 + (o & 7);
                float r = bf2f(xbs[si]);
                xout[si] = f2bf(acc[i][nt][reg] + r);
            }
        }
    }
}

// ---------------- conv9 + BN + ReLU as implicit-GEMM bf16 MFMA ----------------
__global__ __launch_bounds__(256) void conv9_mfma(
    const short8* __restrict__ xr8, const short* __restrict__ bt_g,
    const float* __restrict__ gamma, const float* __restrict__ beta,
    const float* __restrict__ mean, const float* __restrict__ var,
    float* __restrict__ out)
{
    __shared__ short8 patch[8*325];
    __shared__ short8 btl[16*73];
    const int tid = threadIdx.x;
    const int bx = blockIdx.x, by = blockIdx.y, n = blockIdx.z;

    for (int i = tid; i < 1168; i += 256) btl[i] = ((const short8*)bt_g)[i];
    for (int i = tid; i < 2592; i += 256) {
        int c8 = i / 324, r = i - c8*324;
        int py = r / 18, px = r - py*18;
        int gy = by*16 - 1 + py, gx = bx*16 - 1 + px;
        short8 v = {0,0,0,0,0,0,0,0};
        if ((unsigned)gy < 128u && (unsigned)gx < 128u)
            v = xr8[(size_t)(n*8 + c8)*HW_ + gy*W_ + gx];
        patch[c8*325 + py*18 + px] = v;
    }
    __syncthreads();

    const int lane = tid & 63, wid = tid >> 6;
    const int q = lane >> 4, col = lane & 15;
    float4_ acc[4];
    #pragma unroll
    for (int i = 0; i < 4; i++) acc[i] = (float4_){0.f,0.f,0.f,0.f};

    #pragma unroll 2
    for (int k0 = 0; k0 < 18; k0++) {
        int t = k0 >> 1;
        int dy = t/3, dx = t - dy*3;
        int c8 = (k0 & 1)*4 + q;
        short8 b0 = btl[col*73 + k0*4 + q];
        #pragma unroll
        for (int i = 0; i < 4; i++) {
            int mt = wid*4 + i;
            short8 a = patch[c8*325 + (mt + dy)*18 + (col + dx)];
            acc[i] = __builtin_amdgcn_mfma_f32_16x16x32_bf16(a, b0, acc[i], 0,0,0);
        }
    }

    float sc = 0.f, sh = 0.f;
    if (col < 9) {
        sc = gamma[col] * rsqrtf(var[col] + BN_EPS);
        sh = beta[col] - mean[col] * sc;
    }
    #pragma unroll
    for (int i = 0; i < 4; i++) {
        int ty = wid*4 + i;
        if (col < 9) {
            #pragma unroll
            for (int reg = 0; reg < 4; reg++) {
                int tx = q*4 + reg;
                int pix = (by*16 + ty)*W_ + bx*16 + tx;
                float h = fmaxf(fmaf(acc[i][reg], sc, sh), 0.f);
                out[((size_t)n*9 + col)*HW_ + pix] = h;
            }
        }
    }
}

extern "C" void kernel_launch(void* const* d_in, const int* in_sizes, int n_in,
                              void* d_out, int out_size, void* d_ws, size_t ws_size,
                              hipStream_t stream)
{
    const float* x     = (const float*)d_in[0];
    const float* w_off = (const float*)d_in[1];
    const float* w_def = (const float*)d_in[2];
    const float* w1    = (const float*)d_in[3];
    const float* gamma = (const float*)d_in[4];
    const float* beta  = (const float*)d_in[5];
    const float* mean  = (const float*)d_in[6];
    const float* var   = (const float*)d_in[7];
    float* out = (float*)d_out;

    char* ws = (char*)d_ws;
    float*  off_buf = (float*)(ws + OFFB_OFS);
    short8* xb8     = (short8*)(ws + XB8_OFS);
    short8* xr8     = (short8*)(ws + XR8_OFS);
    short*  wdefB   = (short*)(ws + WDEFB_OFS);
    short*  bt27    = (short*)(ws + BT27_OFS);
    short*  bt9     = (short*)(ws + BT9_OFS);

    float* h_out    = out;
    float* filt_out = out + (size_t)N_ * 9 * HW_;

    prep_w<<<dim3(254), dim3(256), 0, stream>>>(w_off, w_def, w1, wdefB, bt27, bt9);
    convert_x<<<dim3(4096), dim3(256), 0, stream>>>(x, xb8);

    dim3 cgrid(8, 8, 8);
    conv27_mfma<<<cgrid, dim3(256), 0, stream>>>(xb8, bt27, off_buf, filt_out);
    deform_mfma<<<cgrid, dim3(256), 0, stream>>>(off_buf, xb8, (const short8*)wdefB, (short*)xr8);
    conv9_mfma<<<cgrid, dim3(256), 0, stream>>>(xr8, bt9, gamma, beta, mean, var, h_out);
}

// Round 4
// 172.009 us; speedup vs baseline: 4.6827x; 1.1085x over previous
//
#include <hip/hip_runtime.h>
#include <cmath>

#define H_ 128
#define W_ 128
#define HW_ 16384
#define C_ 64
#define N_ 8
#define BN_EPS 1e-5f

typedef __attribute__((ext_vector_type(8))) short short8;
typedef __attribute__((ext_vector_type(4))) float float4_;

__device__ inline short f2bf(float f) {
    unsigned u = __builtin_bit_cast(unsigned, f);
    u += 0x7fffu + ((u >> 16) & 1u);     // RNE
    return (short)(u >> 16);
}
__device__ inline float bf2f(short s) {
    unsigned u = ((unsigned)(unsigned short)s) << 16;
    return __builtin_bit_cast(float, u);
}

// ---- workspace layout (bytes) ----
#define OFFB_OFS   0
#define XB8_OFS    9437184
#define XR8_OFS    26214400
#define WDEFB_OFS  42991616
#define BT27_OFS   43065344
#define BT9_OFS    43102720

// ---------------- weight prep ----------------
__global__ __launch_bounds__(256) void prep_w(
    const float* __restrict__ w_off, const float* __restrict__ w_def,
    const float* __restrict__ w1, short* __restrict__ wdefB,
    short* __restrict__ bt27, short* __restrict__ bt9)
{
    int i = blockIdx.x * 256 + threadIdx.x;
    if (i < 36864) {
        int o = i / 576, r = i - o*576, t = r >> 6, c = r & 63;
        wdefB[i] = f2bf(w_def[o*576 + c*9 + t]);
    } else if (i < 36864 + 18688) {
        int j = i - 36864;
        int oc = j / 584, K = j - oc*584;
        float v = 0.f;
        if (oc < 27 && K < 576) { int t = K >> 6, c = K & 63; v = w_off[oc*576 + c*9 + t]; }
        bt27[j] = f2bf(v);
    } else if (i < 36864 + 18688 + 9344) {
        int j = i - 36864 - 18688;
        int oc = j / 584, K = j - oc*584;
        float v = 0.f;
        if (oc < 9 && K < 576) { int t = K >> 6, c = K & 63; v = w1[oc*576 + c*9 + t]; }
        bt9[j] = f2bf(v);
    }
}

// ---------------- x -> NC8HW8 bf16 ----------------
__global__ __launch_bounds__(256) void convert_x(
    const float* __restrict__ x, short8* __restrict__ xb8)
{
    int idx = blockIdx.x * 256 + threadIdx.x;     // [n][c8][pix]
    int pix = idx & (HW_-1);
    int c8  = (idx >> 14) & 7;
    int n   = idx >> 17;
    const float* xp = x + ((size_t)(n*64 + c8*8))*HW_ + pix;
    short8 v;
    #pragma unroll
    for (int j = 0; j < 8; j++) v[j] = f2bf(xp[j*HW_]);
    xb8[idx] = v;
}

// ---------------- conv27 as implicit-GEMM bf16 MFMA ----------------
__global__ __launch_bounds__(256) void conv27_mfma(
    const short8* __restrict__ xb8, const short* __restrict__ bt_g,
    float* __restrict__ off_buf, float* __restrict__ filt_out)
{
    __shared__ short8 patch[8*325];   // [c8][py*18+px], plane stride 325
    __shared__ short8 btl[32*73];     // [oc][K/8]
    const int tid = threadIdx.x;
    const int bx = blockIdx.x, by = blockIdx.y, n = blockIdx.z;

    for (int i = tid; i < 2336; i += 256) btl[i] = ((const short8*)bt_g)[i];
    for (int i = tid; i < 2592; i += 256) {
        int c8 = i / 324, r = i - c8*324;
        int py = r / 18, px = r - py*18;
        int gy = by*16 - 1 + py, gx = bx*16 - 1 + px;
        short8 v = {0,0,0,0,0,0,0,0};
        if ((unsigned)gy < 128u && (unsigned)gx < 128u)
            v = xb8[(size_t)(n*8 + c8)*HW_ + gy*W_ + gx];
        patch[c8*325 + py*18 + px] = v;
    }
    __syncthreads();

    const int lane = tid & 63, wid = tid >> 6;
    const int q = lane >> 4, col = lane & 15;
    float4_ acc[4][2];
    #pragma unroll
    for (int i = 0; i < 4; i++) {
        acc[i][0] = (float4_){0.f,0.f,0.f,0.f};
        acc[i][1] = (float4_){0.f,0.f,0.f,0.f};
    }

    #pragma unroll 2
    for (int k0 = 0; k0 < 18; k0++) {
        int t = k0 >> 1;
        int dy = t/3, dx = t - dy*3;
        int c8 = (k0 & 1)*4 + q;
        short8 b0 = btl[col*73 + k0*4 + q];
        short8 b1 = btl[(16 + col)*73 + k0*4 + q];
        #pragma unroll
        for (int i = 0; i < 4; i++) {
            int mt = wid*4 + i;
            short8 a = patch[c8*325 + (mt + dy)*18 + (col + dx)];
            acc[i][0] = __builtin_amdgcn_mfma_f32_16x16x32_bf16(a, b0, acc[i][0], 0,0,0);
            acc[i][1] = __builtin_amdgcn_mfma_f32_16x16x32_bf16(a, b1, acc[i][1], 0,0,0);
        }
    }

    #pragma unroll
    for (int i = 0; i < 4; i++) {
        int ty = wid*4 + i;
        #pragma unroll
        for (int nt = 0; nt < 2; nt++) {
            int oc = nt*16 + col;
            if (oc >= 27) continue;
            #pragma unroll
            for (int reg = 0; reg < 4; reg++) {
                int tx = q*4 + reg;
                int pix = (by*16 + ty)*W_ + bx*16 + tx;
                float v = acc[i][nt][reg];
                if (oc < 18) off_buf[((size_t)n*18 + oc)*HW_ + pix] = v;
                else         filt_out[((size_t)n*9 + (oc-18))*HW_ + pix] = v;
            }
        }
    }
}

// ---------------- deformable conv as MFMA GEMM, LDS-staged samples ----------------
// block = 16x16 px tile (4 waves), M=256, N=64, K=576 (t*64+c).
// Stage a 22x22 halo patch (all 64 ch, bf16) in LDS once; all bilinear corner
// reads hit LDS (ds_read_b128). Samples outside the patch window (|off|>=~2,
// ~8 sigma) fall back to global reads -- correct for ANY offset value.
__global__ __launch_bounds__(256, 2) void deform_mfma(
    const float* __restrict__ off_buf, const short8* __restrict__ xb8,
    const short8* __restrict__ wdefB, short* __restrict__ xr8s)
{
    __shared__ short8 patch[8*484];   // [c8][py*22+px], 61,952 B
    const int tid = threadIdx.x;
    const int bx = blockIdx.x, by = blockIdx.y, n = blockIdx.z;
    const int lane = tid & 63, wid = tid >> 6;
    const int q = lane >> 4, col = lane & 15;
    const int r0 = by*16 - 3, c0 = bx*16 - 3;
    const float*  ob    = off_buf + (size_t)n*18*HW_;
    const short8* xbase = xb8 + (size_t)n*8*HW_;
    const short*  xbs   = (const short*)xbase;

    for (int i = tid; i < 3872; i += 256) {
        int c8 = i / 484, r = i - c8*484;
        int py = r / 22, px = r - py*22;
        int gy = r0 + py, gx = c0 + px;
        short8 v = {0,0,0,0,0,0,0,0};
        if ((unsigned)gy < 128u && (unsigned)gx < 128u)
            v = xbase[(size_t)c8*HW_ + gy*W_ + gx];
        patch[c8*484 + r] = v;
    }
    __syncthreads();

    const int gxc = bx*16 + col;
    int pixi[4];
    #pragma unroll
    for (int i = 0; i < 4; i++) pixi[i] = (by*16 + wid*4 + i)*W_ + gxc;

    float4_ acc[4][4];
    #pragma unroll
    for (int i = 0; i < 4; i++)
        #pragma unroll
        for (int nt = 0; nt < 4; nt++) acc[i][nt] = (float4_){0.f,0.f,0.f,0.f};

    float oy[4], ox[4];
    #pragma unroll
    for (int i = 0; i < 4; i++) { oy[i] = ob[pixi[i]]; ox[i] = ob[HW_ + pixi[i]]; }

    #pragma unroll 1
    for (int t = 0; t < 9; t++) {
        const int dy = t/3 - 1, dx = (t - (t/3)*3) - 1;
        float oyn[4], oxn[4];
        if (t < 8) {
            #pragma unroll
            for (int i = 0; i < 4; i++) {
                oyn[i] = ob[(2*t+2)*HW_ + pixi[i]];
                oxn[i] = ob[(2*t+3)*HW_ + pixi[i]];
            }
        }
        short8 afrag[4][2];
        #pragma unroll
        for (int i = 0; i < 4; i++) {
            const int gy = by*16 + wid*4 + i;
            float py = (float)(gy + dy) + oy[i];
            float px = (float)(gxc + dx) + ox[i];
            float y0f = floorf(py), x0f = floorf(px);
            float wy1 = py - y0f, wx1 = px - x0f;
            float wy0 = 1.f - wy1, wx0 = 1.f - wx1;
            int y0 = (int)y0f, x0 = (int)x0f;
            int y1 = y0 + 1,   x1 = x0 + 1;
            float vy0 = ((unsigned)y0 < (unsigned)H_) ? 1.f : 0.f;
            float vy1 = ((unsigned)y1 < (unsigned)H_) ? 1.f : 0.f;
            float vx0 = ((unsigned)x0 < (unsigned)W_) ? 1.f : 0.f;
            float vx1 = ((unsigned)x1 < (unsigned)W_) ? 1.f : 0.f;
            float w00 = wy0*wx0*vy0*vx0, w01 = wy0*wx1*vy0*vx1;
            float w10 = wy1*wx0*vy1*vx0, w11 = wy1*wx1*vy1*vx1;
            int cy0 = min(max(y0, 0), H_-1), cy1 = min(max(y1, 0), H_-1);
            int cx0 = min(max(x0, 0), W_-1), cx1 = min(max(x1, 0), W_-1);
            int ly0 = cy0 - r0, ly1 = cy1 - r0;
            int lx0 = cx0 - c0, lx1 = cx1 - c0;
            bool inp = ((unsigned)ly0 < 22u) & ((unsigned)ly1 < 22u)
                     & ((unsigned)lx0 < 22u) & ((unsigned)lx1 < 22u);
            #pragma unroll
            for (int ks = 0; ks < 2; ks++) {
                const int c8 = ks*4 + q;
                short8 p00, p01, p10, p11;
                if (inp) {
                    const short8* pl = &patch[c8*484];
                    p00 = pl[ly0*22 + lx0]; p01 = pl[ly0*22 + lx1];
                    p10 = pl[ly1*22 + lx0]; p11 = pl[ly1*22 + lx1];
                } else {
                    const short8* xg = xbase + (size_t)c8*HW_;
                    p00 = xg[cy0*W_ + cx0]; p01 = xg[cy0*W_ + cx1];
                    p10 = xg[cy1*W_ + cx0]; p11 = xg[cy1*W_ + cx1];
                }
                short8 a;
                #pragma unroll
                for (int j = 0; j < 8; j++) {
                    float s = bf2f(p00[j])*w00 + bf2f(p01[j])*w01
                            + bf2f(p10[j])*w10 + bf2f(p11[j])*w11;
                    a[j] = f2bf(s);
                }
                afrag[i][ks] = a;
            }
        }
        #pragma unroll
        for (int ks = 0; ks < 2; ks++) {
            #pragma unroll
            for (int nt = 0; nt < 4; nt++) {
                short8 b = wdefB[(size_t)(nt*16 + col)*72 + t*8 + ks*4 + q];
                #pragma unroll
                for (int i = 0; i < 4; i++)
                    acc[i][nt] = __builtin_amdgcn_mfma_f32_16x16x32_bf16(
                        afrag[i][ks], b, acc[i][nt], 0,0,0);
            }
        }
        #pragma unroll
        for (int i = 0; i < 4; i++) { oy[i] = oyn[i]; ox[i] = oxn[i]; }
    }

    // epilogue: D col = lane&15 -> oc offset, row = q*4+reg -> tx; +bf16 residual
    short* xout = xr8s + (size_t)n*8*HW_*8;
    #pragma unroll
    for (int i = 0; i < 4; i++) {
        const int gy = by*16 + wid*4 + i;
        #pragma unroll
        for (int nt = 0; nt < 4; nt++) {
            const int o = nt*16 + col;
            #pragma unroll
            for (int reg = 0; reg < 4; reg++) {
                const int gx = bx*16 + q*4 + reg;
                const int pix = gy*W_ + gx;
                size_t si = ((size_t)(o >> 3)*HW_ + pix)*8 + (o & 7);
                float r = bf2f(xbs[si]);
                xout[si] = f2bf(acc[i][nt][reg] + r);
            }
        }
    }
}

// ---------------- conv9 + BN + ReLU as implicit-GEMM bf16 MFMA ----------------
__global__ __launch_bounds__(256) void conv9_mfma(
    const short8* __restrict__ xr8, const short* __restrict__ bt_g,
    const float* __restrict__ gamma, const float* __restrict__ beta,
    const float* __restrict__ mean, const float* __restrict__ var,
    float* __restrict__ out)
{
    __shared__ short8 patch[8*325];
    __shared__ short8 btl[16*73];
    const int tid = threadIdx.x;
    const int bx = blockIdx.x, by = blockIdx.y, n = blockIdx.z;

    for (int i = tid; i < 1168; i += 256) btl[i] = ((const short8*)bt_g)[i];
    for (int i = tid; i < 2592; i += 256) {
        int c8 = i / 324, r = i - c8*324;
        int py = r / 18, px = r - py*18;
        int gy = by*16 - 1 + py, gx = bx*16 - 1 + px;
        short8 v = {0,0,0,0,0,0,0,0};
        if ((unsigned)gy < 128u && (unsigned)gx < 128u)
            v = xr8[(size_t)(n*8 + c8)*HW_ + gy*W_ + gx];
        patch[c8*325 + py*18 + px] = v;
    }
    __syncthreads();

    const int lane = tid & 63, wid = tid >> 6;
    const int q = lane >> 4, col = lane & 15;
    float4_ acc[4];
    #pragma unroll
    for (int i = 0; i < 4; i++) acc[i] = (float4_){0.f,0.f,0.f,0.f};

    #pragma unroll 2
    for (int k0 = 0; k0 < 18; k0++) {
        int t = k0 >> 1;
        int dy = t/3, dx = t - dy*3;
        int c8 = (k0 & 1)*4 + q;
        short8 b0 = btl[col*73 + k0*4 + q];
        #pragma unroll
        for (int i = 0; i < 4; i++) {
            int mt = wid*4 + i;
            short8 a = patch[c8*325 + (mt + dy)*18 + (col + dx)];
            acc[i] = __builtin_amdgcn_mfma_f32_16x16x32_bf16(a, b0, acc[i], 0,0,0);
        }
    }

    float sc = 0.f, sh = 0.f;
    if (col < 9) {
        sc = gamma[col] * rsqrtf(var[col] + BN_EPS);
        sh = beta[col] - mean[col] * sc;
    }
    #pragma unroll
    for (int i = 0; i < 4; i++) {
        int ty = wid*4 + i;
        if (col < 9) {
            #pragma unroll
            for (int reg = 0; reg < 4; reg++) {
                int tx = q*4 + reg;
                int pix = (by*16 + ty)*W_ + bx*16 + tx;
                float h = fmaxf(fmaf(acc[i][reg], sc, sh), 0.f);
                out[((size_t)n*9 + col)*HW_ + pix] = h;
            }
        }
    }
}

extern "C" void kernel_launch(void* const* d_in, const int* in_sizes, int n_in,
                              void* d_out, int out_size, void* d_ws, size_t ws_size,
                              hipStream_t stream)
{
    const float* x     = (const float*)d_in[0];
    const float* w_off = (const float*)d_in[1];
    const float* w_def = (const float*)d_in[2];
    const float* w1    = (const float*)d_in[3];
    const float* gamma = (const float*)d_in[4];
    const float* beta  = (const float*)d_in[5];
    const float* mean  = (const float*)d_in[6];
    const float* var   = (const float*)d_in[7];
    float* out = (float*)d_out;

    char* ws = (char*)d_ws;
    float*  off_buf = (float*)(ws + OFFB_OFS);
    short8* xb8     = (short8*)(ws + XB8_OFS);
    short8* xr8     = (short8*)(ws + XR8_OFS);
    short*  wdefB   = (short*)(ws + WDEFB_OFS);
    short*  bt27    = (short*)(ws + BT27_OFS);
    short*  bt9     = (short*)(ws + BT9_OFS);

    float* h_out    = out;
    float* filt_out = out + (size_t)N_ * 9 * HW_;

    prep_w<<<dim3(254), dim3(256), 0, stream>>>(w_off, w_def, w1, wdefB, bt27, bt9);
    convert_x<<<dim3(4096), dim3(256), 0, stream>>>(x, xb8);

    dim3 cgrid(8, 8, 8);
    conv27_mfma<<<cgrid, dim3(256), 0, stream>>>(xb8, bt27, off_buf, filt_out);
    deform_mfma<<<cgrid, dim3(256), 0, stream>>>(off_buf, xb8, (const short8*)wdefB, (short*)xr8);
    conv9_mfma<<<cgrid, dim3(256), 0, stream>>>(xr8, bt9, gamma, beta, mean, var, h_out);
}